// Round 4
// baseline (68.735 us; speedup 1.0000x reference)
//
#include <hip/hip_runtime.h>

#define BATCH 524288
#define TPB 256

typedef _Float16 half8 __attribute__((ext_vector_type(8)));
typedef float f32x4 __attribute__((ext_vector_type(4)));

// sin/cos of (0.5*angle) via native v_sin_f32 / v_cos_f32 (input in
// revolutions: sin(2*pi*r)).  r = angle * 0.5 / (2*pi).  All our angles are
// |angle| < ~8 -> |r| < 0.7, well inside the accurate range of the HW trig.
// Replaces the ocml __sincosf call path (~50 branchy insts + out-pointers).
#define HSINCOS(angle, s, c)                                  \
    {                                                         \
        const float r_ = (angle) * 0.07957747154594767f;      \
        (s) = __builtin_amdgcn_sinf(r_);                      \
        (c) = __builtin_amdgcn_cosf(r_);                      \
    }

// ---------------------------------------------------------------------------
// Single fused kernel.
//  Phase A (threads 0..15): weight-only 16x16 unitary -> Ub (stride 36).
//  Phase B (all): per-sample product state -> exact f16 hi/lo -> swizzled Sb.
//  ONE barrier.
//  Phase C: A-frags from Ub (one-time ds_read_b128 x4), 4 MFMA tiles per wave
//   (v_mfma_f32_16x16x32_f16, K=32=[S_hi|S_lo], A=[U_hi|U_hi] then [U_lo|U_lo]
//   accumulating -> S*U exact to ~2^-22).  C/D: col(sample)=lane&15,
//   row(j)=(lane>>4)*4+reg.  p=|amp|^2 lane-local; <Z_i> via 7-op combine +
//   2 shfl_xor stages; lanes<16 store float4.
//  __launch_bounds__(256,8): 18.25KB LDS x 8 = 146KB/CU, 64-VGPR budget ->
//   whole 2048-block grid resident in one pass (32 waves/CU).
// ---------------------------------------------------------------------------
__global__ __launch_bounds__(TPB, 8) void qfused_kernel(const float* __restrict__ x,
                                                        const float* __restrict__ w,
                                                        float* __restrict__ out) {
    __shared__ __align__(16) float    Ub[16 * 36];   // 2.25 KB
    __shared__ __align__(16) _Float16 Sb[TPB * 32];  // 16 KB

    const int tid  = threadIdx.x;
    const int lane = tid & 63;
    const int wave = tid >> 6;
    const int l15  = lane & 15;
    const int lg   = lane >> 4;

    // ---- Phase A: build U columns (16 builder threads)
    if (tid < 16) {
        float stx[16], sty[16];
        #pragma unroll
        for (int i = 0; i < 16; i++) { stx[i] = 0.f; sty[i] = 0.f; }
        stx[tid] = 1.f;

        #pragma unroll
        for (int l = 0; l < 2; l++) {
            #pragma unroll
            for (int q = 0; q < 4; q++) {
                float cz, sz, cy, sy;
                HSINCOS(w[l * 8 + q * 2 + 0], sz, cz);
                HSINCOS(w[l * 8 + q * 2 + 1], sy, cy);
                const int mask = 8 >> q;
                // RZ(t) = diag(e^{-it/2}, e^{+it/2})
                #pragma unroll
                for (int i = 0; i < 16; i++) {
                    float ax = stx[i], ay = sty[i];
                    if (i & mask) { stx[i] = ax * cz - ay * sz; sty[i] = ay * cz + ax * sz; }
                    else          { stx[i] = ax * cz + ay * sz; sty[i] = ay * cz - ax * sz; }
                }
                // RY(t) = [[c,-s],[s,c]]
                #pragma unroll
                for (int i = 0; i < 16; i++) {
                    if (!(i & mask)) {
                        float a0x = stx[i], a0y = sty[i];
                        float a1x = stx[i | mask], a1y = sty[i | mask];
                        stx[i]        = cy * a0x - sy * a1x;
                        sty[i]        = cy * a0y - sy * a1y;
                        stx[i | mask] = sy * a0x + cy * a1x;
                        sty[i | mask] = sy * a0y + cy * a1y;
                    }
                }
            }
            // CNOT ring (0,1),(1,2),(2,3),(3,0); wire 0 is MSB (bit 3)
            #pragma unroll
            for (int e = 0; e < 4; e++) {
                const int cqs[4] = {0, 1, 2, 3};
                const int tqs[4] = {1, 2, 3, 0};
                const int cm = 8 >> cqs[e];
                const int tm = 8 >> tqs[e];
                #pragma unroll
                for (int i = 0; i < 16; i++) {
                    if ((i & cm) && !(i & tm)) {
                        float t0x = stx[i], t0y = sty[i];
                        stx[i] = stx[i | tm]; sty[i] = sty[i | tm];
                        stx[i | tm] = t0x;    sty[i | tm] = t0y;
                    }
                }
            }
        }
        #pragma unroll
        for (int j = 0; j < 16; j++) {
            Ub[j * 36 + tid]      = stx[j];   // Re U[j][tid]
            Ub[j * 36 + 16 + tid] = sty[j];   // Im U[j][tid]
        }
    }

    // ---- Phase B: per-thread product state -> f16 hi/lo -> Sb
    const int samp = blockIdx.x * TPB + tid;
    const float4 xv = reinterpret_cast<const float4*>(x)[samp];
    float c0, s0, c1, s1, c2, s2, c3, s3;
    HSINCOS(xv.x, s0, c0);
    HSINCOS(xv.y, s1, c1);
    HSINCOS(xv.z, s2, c2);
    HSINCOS(xv.w, s3, c3);
    const float p01[4] = {c0 * c1, c0 * s1, s0 * c1, s0 * s1};
    const float p23[4] = {c2 * c3, c2 * s3, s2 * c3, s2 * s3};
    half8 ch[4];  // 0,1 = hi[0..7],hi[8..15]; 2,3 = lo[0..7],lo[8..15]
    #pragma unroll
    for (int i = 0; i < 16; i++) {
        const float sv = p01[i >> 2] * p23[i & 3];
        const _Float16 h = (_Float16)sv;
        ch[i >> 3][i & 7]       = h;
        ch[2 + (i >> 3)][i & 7] = (_Float16)(sv - (float)h);
    }
    {
        _Float16* rowp = Sb + tid * 32;
        const int swz = (tid >> 1) & 3;
        #pragma unroll
        for (int c = 0; c < 4; c++)
            *reinterpret_cast<half8*>(rowp + ((c ^ swz) * 8)) = ch[c];
    }
    __syncthreads();

    // ---- Phase C: A-fragments from Ub (one-time LDS read), then MFMA tiles
    const int k8 = (lg & 1) * 8;
    const float* urow = Ub + l15 * 36 + k8;
    const float4 r0 = *reinterpret_cast<const float4*>(urow);
    const float4 r1 = *reinterpret_cast<const float4*>(urow + 4);
    const float4 i0 = *reinterpret_cast<const float4*>(urow + 16);
    const float4 i1 = *reinterpret_cast<const float4*>(urow + 20);
    const float ur[8] = {r0.x, r0.y, r0.z, r0.w, r1.x, r1.y, r1.z, r1.w};
    const float ui[8] = {i0.x, i0.y, i0.z, i0.w, i1.x, i1.y, i1.z, i1.w};
    half8 a_rh, a_rl, a_ih, a_il;
    #pragma unroll
    for (int i = 0; i < 8; i++) {
        const _Float16 h = (_Float16)ur[i];
        a_rh[i] = h;
        a_rl[i] = (_Float16)(ur[i] - (float)h);
        const _Float16 g = (_Float16)ui[i];
        a_ih[i] = g;
        a_il[i] = (_Float16)(ui[i] - (float)g);
    }

    const int rs = lg ^ ((l15 >> 1) & 3);                    // lane-constant read swizzle
    const _Float16* rp = Sb + (wave * 64 + l15) * 32 + rs * 8;
    const int obase = blockIdx.x * TPB + wave * 64;

    #pragma unroll
    for (int T = 0; T < 4; T++) {
        const half8 b = *reinterpret_cast<const half8*>(rp + T * 512);
        f32x4 cre = {0.f, 0.f, 0.f, 0.f}, cim = {0.f, 0.f, 0.f, 0.f};
        cre = __builtin_amdgcn_mfma_f32_16x16x32_f16(a_rh, b, cre, 0, 0, 0);
        cre = __builtin_amdgcn_mfma_f32_16x16x32_f16(a_rl, b, cre, 0, 0, 0);
        cim = __builtin_amdgcn_mfma_f32_16x16x32_f16(a_ih, b, cim, 0, 0, 0);
        cim = __builtin_amdgcn_mfma_f32_16x16x32_f16(a_il, b, cim, 0, 0, 0);

        // p_r = |amp_{j=4*lg+r}|^2 for sample s=l15 (of this tile)
        const float q0 = fmaf(cre[0], cre[0], cim[0] * cim[0]);
        const float q1 = fmaf(cre[1], cre[1], cim[1] * cim[1]);
        const float q2 = fmaf(cre[2], cre[2], cim[2] * cim[2]);
        const float q3 = fmaf(cre[3], cre[3], cim[3] * cim[3]);
        // j = 4*lg + r:  bit3(j)=lg&2, bit2(j)=lg&1, bit1(j)=r&2, bit0(j)=r&1
        const float s01 = q0 + q1, s23 = q2 + q3;
        const float t = s01 + s23;                 // sum over r
        const float u = s01 - s23;                 // Z2 partial (sign by r&2)
        const float v = (q0 - q1) + (q2 - q3);     // Z3 partial (sign by r&1)
        // stage 1: xor 16 (lg^1)
        const float tx = __shfl_xor(t, 16);
        const float t1 = t + tx;
        const float z1 = t - tx;                   // valid in lg even
        const float u1 = u + __shfl_xor(u, 16);
        const float v1 = v + __shfl_xor(v, 16);
        // stage 2: xor 32 (lg^2); results valid in lanes 0..15, which store
        const float z0  = t1 - __shfl_xor(t1, 32);
        const float z1f = z1 + __shfl_xor(z1, 32);
        const float z2  = u1 + __shfl_xor(u1, 32);
        const float z3  = v1 + __shfl_xor(v1, 32);

        if (lane < 16)
            reinterpret_cast<float4*>(out)[obase + T * 16 + l15] =
                make_float4(z0, z1f, z2, z3);
    }
}

extern "C" void kernel_launch(void* const* d_in, const int* in_sizes, int n_in,
                              void* d_out, int out_size, void* d_ws, size_t ws_size,
                              hipStream_t stream) {
    const float* x = (const float*)d_in[0];
    const float* w = (const float*)d_in[1];
    float* out = (float*)d_out;
    (void)d_ws; (void)ws_size;

    const int grid = BATCH / TPB;  // 2048 blocks, 1 sample/thread
    qfused_kernel<<<grid, TPB, 0, stream>>>(x, w, out);
}